// Round 7
// baseline (366.963 us; speedup 1.0000x reference)
//
#include <hip/hip_runtime.h>
#include <hip/hip_bf16.h>

typedef __attribute__((ext_vector_type(8))) short short8;
typedef __attribute__((ext_vector_type(8))) unsigned short ushort8;
typedef __attribute__((ext_vector_type(4))) float floatx4;

#define AS_STRIDE 72   // 64 cin + 8 pad -> 16B-aligned b128

// ws layout: [0, 1179648) kerF (1024x576 bf16, fragment order). xpad REMOVED:
// conv reads x directly and converts during LDS staging (round 7).
#define KERF_BYTES (1024 * 576 * 2)

// ---------------------------------------------------------------------------
// Prep kernel: kerF sampling ONLY (72 blocks = 8 samples x 9 taps).
// Fragment cout mapping: co = (nz>>2)*64 + lane15*4 + (nz&3)  (dense per-wave
// epilogue stores).
// lane holds B[k=khalf*32+((lane>>4)&3)*8+j][co]
// ---------------------------------------------------------------------------
__global__ void prep_k(const float* __restrict__ mu,
                       const float* __restrict__ logstd,
                       const float* __restrict__ noise,
                       __hip_bfloat16* __restrict__ kerF) {
  const int bx = blockIdx.x;
  const int tid = threadIdx.x;
  const int s = bx / 9, tap = bx % 9;
  const float* mu_p = mu + tap * 8192;      // [ci][co]
  const float* ls_p = logstd + tap * 8192;
  const float* nz_p = noise + (s * 9 + tap) * 8192;
  for (int f = tid; f < 1024; f += 256) {   // f = khalf*512 + nz*64 + lane
    int khalf = f >> 9;
    int nz = (f >> 6) & 7;
    int lane = f & 63;
    int co = ((nz >> 2) << 6) + (lane & 15) * 4 + (nz & 3);  // DENSE mapping
    int ci0 = khalf * 32 + ((lane >> 4) & 3) * 8;
    short8 frag;
#pragma unroll
    for (int j = 0; j < 8; ++j) {
      int idx = (ci0 + j) * 128 + co;
      float v = mu_p[idx] + nz_p[idx] * expf(ls_p[idx]);
      frag[j] = (short)__bfloat16_as_ushort(__float2bfloat16(v));
    }
    *(short8*)(kerF + ((size_t)((s * 18 + tap * 2 + khalf) * 8 + nz) * 64 + lane) * 8) = frag;
  }
}

// ---------------------------------------------------------------------------
// Conv + ELU, implicit GEMM. Tile = 128 pixels (2 rows x 64 w) x 128 n.
// 4 waves x (4x4 MFMA 16x16x32 bf16). B from global (XCD-local L2).
// Persistent-ish: 1024 blocks x 4 tiles, n_tile fixed per block.
// Round 7: xpad intermediate ELIMINATED — stage reads x (f32, L3-resident)
// directly, converts to bf16 and zero-fills the 1-pixel border in-kernel.
// Removes prep's 2178-block xpad phase + the 8.9MB write / ~68MB re-read
// round trip + shortens the serial prep->conv chain.
// ---------------------------------------------------------------------------
__global__ __launch_bounds__(256, 3)
void conv_elu_k(const float* __restrict__ x,
                const __hip_bfloat16* __restrict__ kerF,
                float* __restrict__ out) {
  __shared__ __hip_bfloat16 As[4 * 66 * AS_STRIDE];  // 38016 B

  const int tid = threadIdx.x;
  const int lane = tid & 63;
  const int lane15 = tid & 15;
  const int quad = (tid >> 4) & 3;
  const int wave = tid >> 6;
  const int n_tile = blockIdx.x & 7;     // 0..7 (= sample s = XCD id), fixed
  const int mt_base = blockIdx.x >> 3;   // 0..127

  const int row_sel = wave >> 1;         // which of the 2 output rows
  const int nz0sel = wave & 1;           // fragment nz half (0 or 1)

  // Invariant per block:
  const __hip_bfloat16* bBase =
      kerF + (size_t)n_tile * 18 * 8 * 64 * 8 + (nz0sel << 2) * 512 + lane * 8;
  const __hip_bfloat16* aRowBase =
      As + (row_sel * 66 + lane15) * AS_STRIDE + quad * 8;

  short8 aE[4], aO[4], bE[4], bO[4];

  auto loadB = [&](short8* dst, const __hip_bfloat16* p) {
#pragma unroll
    for (int ni = 0; ni < 4; ++ni)
      dst[ni] = *(const short8*)(p + ni * 512);
  };
  auto loadA = [&](short8* dst, const __hip_bfloat16* row, int khalfOff) {
#pragma unroll
    for (int mi = 0; mi < 4; ++mi)
      dst[mi] = *(const short8*)(row + khalfOff + mi * 16 * AS_STRIDE);
  };

#pragma unroll 1
  for (int it = 0; it < 4; ++it) {
    const int mt = mt_base + (it << 7);  // 0..511
    const int b = mt >> 5;
    const int h0 = (mt & 31) << 1;

    // ---- Stage A: rows h0-1..h0+2 of x, f32->bf16, zero borders ----
    // c indexes 16B-LDS chunks: r = padded row (0..3), j = padded col (0..65),
    // ci = 8-channel segment. h = h0+r-1, w = j-1 in x coords.
    for (int c = tid; c < 2112; c += 256) {      // 2112 x 16B = 33792 B
      int r = c / 528;                           // 528 chunks per padded row
      int cc = c - r * 528;
      int j = cc >> 3;
      int ci = (cc & 7) << 3;
      int h = h0 + r - 1;
      int w = j - 1;
      ushort8 v = {0, 0, 0, 0, 0, 0, 0, 0};
      if ((unsigned)h < 64u && (unsigned)w < 64u) {
        const float* src = x + ((((size_t)b * 64 + h) * 64 + w) << 6) + ci;
        float4 v0 = *(const float4*)src;
        float4 v1 = *(const float4*)(src + 4);
        v[0] = __bfloat16_as_ushort(__float2bfloat16(v0.x));
        v[1] = __bfloat16_as_ushort(__float2bfloat16(v0.y));
        v[2] = __bfloat16_as_ushort(__float2bfloat16(v0.z));
        v[3] = __bfloat16_as_ushort(__float2bfloat16(v0.w));
        v[4] = __bfloat16_as_ushort(__float2bfloat16(v1.x));
        v[5] = __bfloat16_as_ushort(__float2bfloat16(v1.y));
        v[6] = __bfloat16_as_ushort(__float2bfloat16(v1.z));
        v[7] = __bfloat16_as_ushort(__float2bfloat16(v1.w));
      }
      *(ushort8*)&As[(r * 66 + j) * AS_STRIDE + ci] = v;
    }

    floatx4 acc[4][4] = {};
    const __hip_bfloat16* bPtr = bBase;
    const __hip_bfloat16* aRow = aRowBase;

    __syncthreads();  // A ready

    auto mfmaStep = [&](short8 (&a)[4], short8 (&bb)[4]) {
#pragma unroll
      for (int mi = 0; mi < 4; ++mi)
#pragma unroll
        for (int ni = 0; ni < 4; ++ni)
          acc[mi][ni] = __builtin_amdgcn_mfma_f32_16x16x32_bf16(
              a[mi], bb[ni], acc[mi][ni], 0, 0, 0);
    };

    loadB(bE, bPtr);
    loadA(aE, aRow, 0);
    int kw = 0;
#pragma unroll 1
    for (int tap = 0; tap < 8; ++tap) {
      loadB(bO, bPtr + 4096);            // odd khalf of this tap
      loadA(aO, aRow, 32);
      mfmaStep(aE, bE);
      bPtr += 8192;                      // advance to next tap
      aRow += AS_STRIDE;
      if (++kw == 3) { kw = 0; aRow += 63 * AS_STRIDE; }
      loadB(bE, bPtr);                   // even khalf of next tap
      loadA(aE, aRow, 0);
      mfmaStep(aO, bO);
    }
    loadB(bO, bPtr + 4096);              // tap 8, odd khalf
    loadA(aO, aRow, 32);
    mfmaStep(aE, bE);
    mfmaStep(aO, bO);

    // ---- Epilogue: ELU + dense float4 stores.
    // co = nz0sel*64 + lane15*4 + ni -> wave writes 256 B contiguous/row ----
    const int h = h0 + row_sel;
    float* outp = out + (size_t)((b * 64 + h) * 64) * 1024 +
                  (size_t)(n_tile * 128 + (nz0sel << 6) + (lane15 << 2));
#pragma unroll
    for (int mi = 0; mi < 4; ++mi) {
#pragma unroll
      for (int r = 0; r < 4; ++r) {
        int w = mi * 16 + quad * 4 + r;
        float4 v;
        float e0 = acc[mi][0][r];
        float e1 = acc[mi][1][r];
        float e2 = acc[mi][2][r];
        float e3 = acc[mi][3][r];
        v.x = e0 > 0.f ? e0 : __expf(e0) - 1.f;
        v.y = e1 > 0.f ? e1 : __expf(e1) - 1.f;
        v.z = e2 > 0.f ? e2 : __expf(e2) - 1.f;
        v.w = e3 > 0.f ? e3 : __expf(e3) - 1.f;
        *(float4*)(outp + (size_t)w * 1024) = v;
      }
    }

    if (it < 3) __syncthreads();  // all waves done reading As before re-stage
  }
}

extern "C" void kernel_launch(void* const* d_in, const int* in_sizes, int n_in,
                              void* d_out, int out_size, void* d_ws, size_t ws_size,
                              hipStream_t stream) {
  const float* x      = (const float*)d_in[0];
  const float* mu     = (const float*)d_in[1];
  const float* logstd = (const float*)d_in[2];
  const float* noise  = (const float*)d_in[3];
  float* out = (float*)d_out;
  __hip_bfloat16* kerF = (__hip_bfloat16*)d_ws;

  prep_k<<<72, 256, 0, stream>>>(mu, logstd, noise, kerF);
  conv_elu_k<<<1024, 256, 0, stream>>>(x, kerF, out);
}